// Round 6
// baseline (226.487 us; speedup 1.0000x reference)
//
#include <hip/hip_runtime.h>

// Problem constants (from setup_inputs)
#define BB   4
#define NN   5
#define JJ   15
#define HHH  128
#define WHH  240
#define CBX  80
#define CBY  80
#define CBZ  20
#define PP   (CBX*CBY*CBZ)          // 128000
#define HW   (HHH*WHH)              // 30720
#define IMGW 960.0f
#define IMGH 512.0f

// Lane remap: block = 320 threads = 16 iy (innermost) x 20 iz.
// A wave64 covers a 16(iy) x 4(iz) voxel patch -> adjacent lanes step ~4.3
// heatmap px horizontally in the SAME row -> ~3 lanes share each 64B line,
// cutting L1/TA line-transactions ~1.7x vs the iz-innermost mapping.
__global__ __launch_bounds__(320) void project_kernel(
    const float* __restrict__ hm,      // [N,B,J,H,W]
    const float* __restrict__ Rm,      // [B,N,3,3]
    const float* __restrict__ Tv,      // [B,N,3]
    const float* __restrict__ fv,      // [B,N,2]
    const float* __restrict__ cv,      // [B,N,2]
    const float* __restrict__ trans,   // [B,N,2,3]
    const float* __restrict__ whv,     // [B,N,2]
    const float* __restrict__ gcv,     // [B,3]
    float* __restrict__ out)           // fused [B,J,P] then grids [B,P,3]
{
    int tid = threadIdx.x;             // 0..319
    int bid = blockIdx.x;              // B * 80(ix) * 5(iy-tile)
    int iyt = bid % 5;
    int ix  = (bid / 5) % CBX;
    int b   = bid / (5 * CBX);
    int iyl = tid & 15;
    int iz  = tid >> 4;                // 0..19
    int iy  = iyt * 16 + iyl;
    int p   = ix * (CBY * CBZ) + iy * CBZ + iz;

    const float stx = 8000.0f / (CBX - 1);
    const float sty = 8000.0f / (CBY - 1);
    const float stz = 2000.0f / (CBZ - 1);
    float gx = -4000.0f + (float)ix * stx + gcv[b * 3 + 0];
    float gy = -4000.0f + (float)iy * sty + gcv[b * 3 + 1];
    float gz = -1000.0f + (float)iz * stz + gcv[b * 3 + 2];

    // grids output (second tuple element)
    {
        float* grids_out = out + (size_t)BB * JJ * PP;
        size_t gb = (size_t)(b * PP + p) * 3;
        grids_out[gb + 0] = gx;
        grids_out[gb + 1] = gy;
        grids_out[gb + 2] = gz;
    }

    // Per-view pair-gather state: two row base offsets + 4 pair coefficients
    float wl0[NN], wr0[NN], wl1[NN], wr1[NN];   // e0/e1 coeffs for row0, row1
    int   r0[NN], r1[NN];                       // row base offsets (in floats)
    float bnd[NN];
    float sumb = 0.0f;

    #pragma unroll
    for (int n = 0; n < NN; ++n) {
        int bn = b * NN + n;
        const float* R = Rm + bn * 9;
        float dx = gx - Tv[bn * 3 + 0];
        float dy = gy - Tv[bn * 3 + 1];
        float dz = gz - Tv[bn * 3 + 2];
        float cx = R[0] * dx + R[1] * dy + R[2] * dz;
        float cy = R[3] * dx + R[4] * dy + R[5] * dz;
        float cz = R[6] * dx + R[7] * dy + R[8] * dz;
        float inv = 1.0f / cz;
        float px = cx * inv * fv[bn * 2 + 0] + cv[bn * 2 + 0];
        float py = cy * inv * fv[bn * 2 + 1] + cv[bn * 2 + 1];
        float w = whv[bn * 2 + 0], h = whv[bn * 2 + 1];
        float bound = (px >= 0.0f && py >= 0.0f && px < w && py < h) ? 1.0f : 0.0f;
        float mwh = fmaxf(w, h);
        px = fminf(fmaxf(px, -1.0f), mwh);
        py = fminf(fmaxf(py, -1.0f), mwh);
        const float* tr = trans + bn * 6;
        float tx = tr[0] * px + tr[1] * py + tr[2];
        float ty = tr[3] * px + tr[4] * py + tr[5];
        tx *= (float)WHH / IMGW;   // 0.25
        ty *= (float)HHH / IMGH;   // 0.25
        float sgx = tx / (float)(WHH - 1) * 2.0f - 1.0f;
        float sgy = ty / (float)(HHH - 1) * 2.0f - 1.0f;
        sgx = fminf(fmaxf(sgx, -1.1f), 1.1f);
        sgy = fminf(fmaxf(sgy, -1.1f), 1.1f);
        float xx = (sgx + 1.0f) * 0.5f * (float)(WHH - 1);
        float yy = (sgy + 1.0f) * 0.5f * (float)(HHH - 1);
        float x0f = floorf(xx), y0f = floorf(yy);
        float wx = xx - x0f, wy = yy - y0f;
        int x0 = (int)x0f, y0 = (int)y0f;

        // x-direction pair coefficients for the float2 window at xb.
        float axl, axr;
        if (x0 < 0) {
            float vx1 = (x0 + 1 >= 0) ? 1.0f : 0.0f;   // x0 == -1 only
            axl = wx * vx1;
            axr = 0.0f;
        } else if (x0 >= WHH - 1) {
            float vx0 = (x0 <= WHH - 1) ? 1.0f : 0.0f; // x0 == W-1 only
            axl = 0.0f;
            axr = (1.0f - wx) * vx0;
        } else {
            axl = 1.0f - wx;
            axr = wx;
        }
        int xb = min(max(x0, 0), WHH - 2);

        float vy0 = (y0 >= 0 && y0 <= HHH - 1) ? 1.0f : 0.0f;
        float vy1 = (y0 + 1 >= 0 && y0 + 1 <= HHH - 1) ? 1.0f : 0.0f;
        int yc0 = min(max(y0, 0), HHH - 1);
        int yc1 = min(max(y0 + 1, 0), HHH - 1);
        float ay0 = (1.0f - wy) * vy0 * bound;
        float ay1 = wy * vy1 * bound;

        wl0[n] = axl * ay0;  wr0[n] = axr * ay0;
        wl1[n] = axl * ay1;  wr1[n] = axr * ay1;
        r0[n] = yc0 * WHH + xb;
        r1[n] = yc1 * WHH + xb;
        bnd[n] = bound;
        sumb += bound;
    }

    float acc[JJ];
    #pragma unroll
    for (int j = 0; j < JJ; ++j) acc[j] = 0.0f;

    // n outer (one wave-coherent branch per view), j inner (30 independent
    // float2 loads per branch body -> deep memory-level parallelism).
    #pragma unroll
    for (int n = 0; n < NN; ++n) {
        if (bnd[n] != 0.0f) {
            const float* base = hm + (size_t)((n * BB + b) * JJ) * HW;
            float c00 = wl0[n], c01 = wr0[n], c10 = wl1[n], c11 = wr1[n];
            int o0 = r0[n], o1 = r1[n];
            #pragma unroll
            for (int j = 0; j < JJ; ++j) {
                const float* pj = base + j * HW;
                float2 e = *reinterpret_cast<const float2*>(pj + o0);
                float2 f2 = *reinterpret_cast<const float2*>(pj + o1);
                acc[j] += c00 * e.x + c01 * e.y + c10 * f2.x + c11 * f2.y;
            }
        }
    }

    float denom = 1.0f / (sumb + 1e-6f);
    size_t outb = (size_t)b * JJ * PP + p;
    #pragma unroll
    for (int j = 0; j < JJ; ++j) {
        float v = acc[j] * denom;
        v = fminf(fmaxf(v, 0.0f), 1.0f);
        out[outb + (size_t)j * PP] = v;
    }
}

extern "C" void kernel_launch(void* const* d_in, const int* in_sizes, int n_in,
                              void* d_out, int out_size, void* d_ws, size_t ws_size,
                              hipStream_t stream) {
    const float* hm    = (const float*)d_in[0];
    const float* Rm    = (const float*)d_in[1];
    const float* Tv    = (const float*)d_in[2];
    const float* fv    = (const float*)d_in[3];
    const float* cv    = (const float*)d_in[4];
    const float* trans = (const float*)d_in[5];
    const float* whv   = (const float*)d_in[6];
    const float* gcv   = (const float*)d_in[7];
    float* out = (float*)d_out;

    int grid = BB * CBX * 5;   // b, ix, iy-tile(16)
    project_kernel<<<grid, 320, 0, stream>>>(hm, Rm, Tv, fv, cv, trans, whv, gcv, out);
}

// Round 7
// 184.389 us; speedup vs baseline: 1.2283x; 1.2283x over previous
//
#include <hip/hip_runtime.h>

// Problem constants (from setup_inputs)
#define BB   4
#define NN   5
#define JJ   15
#define HHH  128
#define WHH  240
#define CBX  80
#define CBY  80
#define CBZ  20
#define PP   (CBX*CBY*CBZ)          // 128000
#define HW   (HHH*WHH)              // 30720
#define IMGW 960.0f
#define IMGH 512.0f
#define NJP  80                     // padded pixel record: 5 views * 16 (15 j + pad)
#define XT   60                     // x-tile for transpose (240 = 4*60)

// ---------------------------------------------------------------------------
// Pass 1: transpose hm [N,B,J,H,W] -> ws [B,H,W,N,16]  (j padded to 16, pad=0)
// Per (y,x) pixel: all (n,j) values contiguous; each (n)-slice of 15 floats
// sits inside ONE 64B-aligned line (x-stride 320B, n-stride 64B).
// Writes: 60*80*4 = 19.2 KB fully contiguous per block. Reads: per x-window of
// 16 the 75 source lines stay hot in L1 across iterations.
// ---------------------------------------------------------------------------
__global__ __launch_bounds__(256) void transpose_kernel(
    const float* __restrict__ hm, float* __restrict__ ws)
{
    int bid = blockIdx.x;              // B * H * (W/XT) = 4*128*4 = 2048
    int xt = bid & 3;
    int y  = (bid >> 2) & (HHH - 1);
    int b  = bid >> 9;                 // bid / (4*128)
    int x0 = xt * XT;
    size_t wsb = ((size_t)(b * HHH + y) * WHH + x0) * NJP;
    const int total = XT * NJP;        // 4800
    for (int off = threadIdx.x; off < total; off += 256) {
        int x = off / NJP;
        int q = off - x * NJP;
        int n = q >> 4;
        int j = q & 15;
        float v = 0.0f;
        if (j < JJ) {
            v = hm[((size_t)(n * BB + b) * JJ + j) * HW + y * WHH + x0 + x];
        }
        ws[wsb + off] = v;
    }
}

// ---------------------------------------------------------------------------
// Pass 2: one thread per (b,p) voxel, iz-innermost (round-5 mapping: best
// gather locality measured, coalesced fused/grids writes).
// ---------------------------------------------------------------------------
__global__ __launch_bounds__(256) void project_kernel(
    const float* __restrict__ ws,      // [B,H,W,N,16] transposed heatmaps
    const float* __restrict__ Rm,      // [B,N,3,3]
    const float* __restrict__ Tv,      // [B,N,3]
    const float* __restrict__ fv,      // [B,N,2]
    const float* __restrict__ cv,      // [B,N,2]
    const float* __restrict__ trans,   // [B,N,2,3]
    const float* __restrict__ whv,     // [B,N,2]
    const float* __restrict__ gcv,     // [B,3]
    float* __restrict__ out)           // fused [B,J,P] then grids [B,P,3]
{
    int t = blockIdx.x * blockDim.x + threadIdx.x;
    if (t >= BB * PP) return;
    int b = t / PP;
    int p = t - b * PP;
    int ix  = p / (CBY * CBZ);
    int rem = p - ix * (CBY * CBZ);
    int iy  = rem / CBZ;
    int iz  = rem - iy * CBZ;

    const float stx = 8000.0f / (CBX - 1);
    const float sty = 8000.0f / (CBY - 1);
    const float stz = 2000.0f / (CBZ - 1);
    float gx = -4000.0f + (float)ix * stx + gcv[b * 3 + 0];
    float gy = -4000.0f + (float)iy * sty + gcv[b * 3 + 1];
    float gz = -1000.0f + (float)iz * stz + gcv[b * 3 + 2];

    // grids output (second tuple element)
    {
        float* grids_out = out + (size_t)BB * JJ * PP;
        size_t gb = (size_t)(b * PP + p) * 3;
        grids_out[gb + 0] = gx;
        grids_out[gb + 1] = gy;
        grids_out[gb + 2] = gz;
    }

    float wl0[NN], wr0[NN], wl1[NN], wr1[NN];   // tap coeffs (row0/1, left/right)
    int   r0[NN], r1[NN];                       // pixel index (y*W + x) per row
    float bnd[NN];
    float sumb = 0.0f;

    #pragma unroll
    for (int n = 0; n < NN; ++n) {
        int bn = b * NN + n;
        const float* R = Rm + bn * 9;
        float dx = gx - Tv[bn * 3 + 0];
        float dy = gy - Tv[bn * 3 + 1];
        float dz = gz - Tv[bn * 3 + 2];
        float cx = R[0] * dx + R[1] * dy + R[2] * dz;
        float cy = R[3] * dx + R[4] * dy + R[5] * dz;
        float cz = R[6] * dx + R[7] * dy + R[8] * dz;
        float inv = 1.0f / cz;
        float px = cx * inv * fv[bn * 2 + 0] + cv[bn * 2 + 0];
        float py = cy * inv * fv[bn * 2 + 1] + cv[bn * 2 + 1];
        float w = whv[bn * 2 + 0], h = whv[bn * 2 + 1];
        float bound = (px >= 0.0f && py >= 0.0f && px < w && py < h) ? 1.0f : 0.0f;
        float mwh = fmaxf(w, h);
        px = fminf(fmaxf(px, -1.0f), mwh);
        py = fminf(fmaxf(py, -1.0f), mwh);
        const float* tr = trans + bn * 6;
        float tx = tr[0] * px + tr[1] * py + tr[2];
        float ty = tr[3] * px + tr[4] * py + tr[5];
        tx *= (float)WHH / IMGW;   // 0.25
        ty *= (float)HHH / IMGH;   // 0.25
        float sgx = tx / (float)(WHH - 1) * 2.0f - 1.0f;
        float sgy = ty / (float)(HHH - 1) * 2.0f - 1.0f;
        sgx = fminf(fmaxf(sgx, -1.1f), 1.1f);
        sgy = fminf(fmaxf(sgy, -1.1f), 1.1f);
        float xx = (sgx + 1.0f) * 0.5f * (float)(WHH - 1);
        float yy = (sgy + 1.0f) * 0.5f * (float)(HHH - 1);
        float x0f = floorf(xx), y0f = floorf(yy);
        float wx = xx - x0f, wy = yy - y0f;
        int x0 = (int)x0f, y0 = (int)y0f;

        // x-direction pair coefficients for the window [xb, xb+1]
        float axl, axr;
        if (x0 < 0) {
            float vx1 = (x0 + 1 >= 0) ? 1.0f : 0.0f;   // x0 == -1 only
            axl = wx * vx1;
            axr = 0.0f;
        } else if (x0 >= WHH - 1) {
            float vx0 = (x0 <= WHH - 1) ? 1.0f : 0.0f; // x0 == W-1 only
            axl = 0.0f;
            axr = (1.0f - wx) * vx0;
        } else {
            axl = 1.0f - wx;
            axr = wx;
        }
        int xb = min(max(x0, 0), WHH - 2);

        float vy0 = (y0 >= 0 && y0 <= HHH - 1) ? 1.0f : 0.0f;
        float vy1 = (y0 + 1 >= 0 && y0 + 1 <= HHH - 1) ? 1.0f : 0.0f;
        int yc0 = min(max(y0, 0), HHH - 1);
        int yc1 = min(max(y0 + 1, 0), HHH - 1);
        float ay0 = (1.0f - wy) * vy0 * bound;
        float ay1 = wy * vy1 * bound;

        wl0[n] = axl * ay0;  wr0[n] = axr * ay0;
        wl1[n] = axl * ay1;  wr1[n] = axr * ay1;
        r0[n] = yc0 * WHH + xb;
        r1[n] = yc1 * WHH + xb;
        bnd[n] = bound;
        sumb += bound;
    }

    float acc[JJ];
    #pragma unroll
    for (int j = 0; j < JJ; ++j) acc[j] = 0.0f;

    size_t base_b = (size_t)b * HHH * WHH * NJP;

    #pragma unroll
    for (int n = 0; n < NN; ++n) {
        if (bnd[n] != 0.0f) {
            size_t a0 = base_b + (size_t)r0[n] * NJP + n * 16;  // 64B-aligned
            size_t a1 = base_b + (size_t)r1[n] * NJP + n * 16;
            const float4* p00 = reinterpret_cast<const float4*>(ws + a0);
            const float4* p01 = reinterpret_cast<const float4*>(ws + a0 + NJP);
            const float4* p10 = reinterpret_cast<const float4*>(ws + a1);
            const float4* p11 = reinterpret_cast<const float4*>(ws + a1 + NJP);
            // unpack to statically-indexed register arrays (no scratch)
            float f00[16], f01[16], f10[16], f11[16];
            #pragma unroll
            for (int k = 0; k < 4; ++k) {
                float4 v0 = p00[k], v1 = p01[k], v2 = p10[k], v3 = p11[k];
                f00[4*k] = v0.x; f00[4*k+1] = v0.y; f00[4*k+2] = v0.z; f00[4*k+3] = v0.w;
                f01[4*k] = v1.x; f01[4*k+1] = v1.y; f01[4*k+2] = v1.z; f01[4*k+3] = v1.w;
                f10[4*k] = v2.x; f10[4*k+1] = v2.y; f10[4*k+2] = v2.z; f10[4*k+3] = v2.w;
                f11[4*k] = v3.x; f11[4*k+1] = v3.y; f11[4*k+2] = v3.z; f11[4*k+3] = v3.w;
            }
            float c00 = wl0[n], c01 = wr0[n], c10 = wl1[n], c11 = wr1[n];
            #pragma unroll
            for (int j = 0; j < JJ; ++j) {
                acc[j] += c00 * f00[j] + c01 * f01[j] + c10 * f10[j] + c11 * f11[j];
            }
        }
    }

    float denom = 1.0f / (sumb + 1e-6f);
    size_t outb = (size_t)b * JJ * PP + p;
    #pragma unroll
    for (int j = 0; j < JJ; ++j) {
        float v = acc[j] * denom;
        v = fminf(fmaxf(v, 0.0f), 1.0f);
        out[outb + (size_t)j * PP] = v;
    }
}

extern "C" void kernel_launch(void* const* d_in, const int* in_sizes, int n_in,
                              void* d_out, int out_size, void* d_ws, size_t ws_size,
                              hipStream_t stream) {
    const float* hm    = (const float*)d_in[0];
    const float* Rm    = (const float*)d_in[1];
    const float* Tv    = (const float*)d_in[2];
    const float* fv    = (const float*)d_in[3];
    const float* cv    = (const float*)d_in[4];
    const float* trans = (const float*)d_in[5];
    const float* whv   = (const float*)d_in[6];
    const float* gcv   = (const float*)d_in[7];
    float* out = (float*)d_out;
    float* ws  = (float*)d_ws;         // needs 4*128*240*80*4 = 39.3 MB

    // Pass 1: heatmap transpose to pixel-major [B,H,W,N,16]
    transpose_kernel<<<BB * HHH * 4, 256, 0, stream>>>(hm, ws);

    // Pass 2: project + gather + fuse
    int total = BB * PP;
    int block = 256;
    int grid  = (total + block - 1) / block;
    project_kernel<<<grid, block, 0, stream>>>(ws, Rm, Tv, fv, cv, trans, whv, gcv, out);
}

// Round 10
// 153.458 us; speedup vs baseline: 1.4759x; 1.2016x over previous
//
#include <hip/hip_runtime.h>
#include <hip/hip_fp16.h>

// Problem constants (from setup_inputs)
#define BB   4
#define NN   5
#define JJ   15
#define HHH  128
#define WHH  240
#define CBX  80
#define CBY  80
#define CBZ  20
#define PP   (CBX*CBY*CBZ)          // 128000
#define HW   (HHH*WHH)              // 30720
#define IMGW 960.0f
#define IMGH 512.0f
#define RECU 16                     // uint32 per record: 15 j-pairs + 1 pad

// ws layout: one 64B record per (b,y,n,x):
//   uint index = (((b*HHH + y)*NN + n)*WHH + x) * RECU + j
//   record[j] = half2( hm[n,b,j,y,x], hm[n,b,j,y,x+1] )   (x+1 clamped to 239)
// -> a bilinear row-tap (both x taps, all 15 joints) = ONE 64B line.

// ---------------------------------------------------------------------------
// Pass 1: LDS-tiled pack. Block = one (b,y,n): 15 coalesced row reads ->
// LDS [15][241] (dup col 240 = col 239) -> coalesced packed-f16 writes.
// ---------------------------------------------------------------------------
__global__ __launch_bounds__(256) void pack_kernel(
    const float* __restrict__ hm, unsigned int* __restrict__ ws)
{
    __shared__ float rows[JJ][WHH + 1];   // 241 cols, ~14.5 KB
    int bid = blockIdx.x;                 // B*H*N = 4*128*5 = 2560
    int n = bid % NN;
    int y = (bid / NN) % HHH;
    int b = bid / (NN * HHH);

    const float* src = hm + ((size_t)(n * BB + b) * JJ) * HW + y * WHH;
    for (int idx = threadIdx.x; idx < JJ * (WHH + 1); idx += 256) {
        int j = idx / (WHH + 1);
        int x = idx - j * (WHH + 1);
        int xs = min(x, WHH - 1);
        rows[j][x] = src[j * HW + xs];
    }
    __syncthreads();

    unsigned int* dst = ws + (size_t)((b * HHH + y) * NN + n) * WHH * RECU;
    for (int idx = threadIdx.x; idx < WHH * RECU; idx += 256) {
        int x = idx >> 4;
        int u = idx & 15;
        unsigned int val = 0u;
        if (u < JJ) {
            __half2 h = __halves2half2(__float2half_rn(rows[u][x]),
                                       __float2half_rn(rows[u][x + 1]));
            val = *reinterpret_cast<unsigned int*>(&h);
        }
        dst[idx] = val;
    }
}

// ---------------------------------------------------------------------------
// Pass 2: one thread per (b,p) voxel, iz-innermost (best measured mapping).
// Per view: 2 record loads (row y0, row y1), each one 64B line.
// ---------------------------------------------------------------------------
__global__ __launch_bounds__(256) void project_kernel(
    const unsigned int* __restrict__ ws,
    const float* __restrict__ Rm,      // [B,N,3,3]
    const float* __restrict__ Tv,      // [B,N,3]
    const float* __restrict__ fv,      // [B,N,2]
    const float* __restrict__ cv,      // [B,N,2]
    const float* __restrict__ trans,   // [B,N,2,3]
    const float* __restrict__ whv,     // [B,N,2]
    const float* __restrict__ gcv,     // [B,3]
    float* __restrict__ out)           // fused [B,J,P] then grids [B,P,3]
{
    int t = blockIdx.x * blockDim.x + threadIdx.x;
    if (t >= BB * PP) return;
    int b = t / PP;
    int p = t - b * PP;
    int ix  = p / (CBY * CBZ);
    int rem = p - ix * (CBY * CBZ);
    int iy  = rem / CBZ;
    int iz  = rem - iy * CBZ;

    const float stx = 8000.0f / (CBX - 1);
    const float sty = 8000.0f / (CBY - 1);
    const float stz = 2000.0f / (CBZ - 1);
    float gx = -4000.0f + (float)ix * stx + gcv[b * 3 + 0];
    float gy = -4000.0f + (float)iy * sty + gcv[b * 3 + 1];
    float gz = -1000.0f + (float)iz * stz + gcv[b * 3 + 2];

    // grids output (second tuple element)
    {
        float* grids_out = out + (size_t)BB * JJ * PP;
        size_t gb = (size_t)(b * PP + p) * 3;
        grids_out[gb + 0] = gx;
        grids_out[gb + 1] = gy;
        grids_out[gb + 2] = gz;
    }

    float cl0[NN], cr0[NN], cl1[NN], cr1[NN];   // folded coeffs per row
    int   r0[NN], r1[NN];                       // record uint index per row
    float bnd[NN];
    float sumb = 0.0f;

    #pragma unroll
    for (int n = 0; n < NN; ++n) {
        int bn = b * NN + n;
        const float* R = Rm + bn * 9;
        float dx = gx - Tv[bn * 3 + 0];
        float dy = gy - Tv[bn * 3 + 1];
        float dz = gz - Tv[bn * 3 + 2];
        float cx = R[0] * dx + R[1] * dy + R[2] * dz;
        float cy = R[3] * dx + R[4] * dy + R[5] * dz;
        float cz = R[6] * dx + R[7] * dy + R[8] * dz;
        float inv = 1.0f / cz;
        float px = cx * inv * fv[bn * 2 + 0] + cv[bn * 2 + 0];
        float py = cy * inv * fv[bn * 2 + 1] + cv[bn * 2 + 1];
        float w = whv[bn * 2 + 0], h = whv[bn * 2 + 1];
        float bound = (px >= 0.0f && py >= 0.0f && px < w && py < h) ? 1.0f : 0.0f;
        float mwh = fmaxf(w, h);
        px = fminf(fmaxf(px, -1.0f), mwh);
        py = fminf(fmaxf(py, -1.0f), mwh);
        const float* tr = trans + bn * 6;
        float tx = tr[0] * px + tr[1] * py + tr[2];
        float ty = tr[3] * px + tr[4] * py + tr[5];
        tx *= (float)WHH / IMGW;   // 0.25
        ty *= (float)HHH / IMGH;   // 0.25
        float sgx = tx / (float)(WHH - 1) * 2.0f - 1.0f;
        float sgy = ty / (float)(HHH - 1) * 2.0f - 1.0f;
        sgx = fminf(fmaxf(sgx, -1.1f), 1.1f);
        sgy = fminf(fmaxf(sgy, -1.1f), 1.1f);
        float xx = (sgx + 1.0f) * 0.5f * (float)(WHH - 1);
        float yy = (sgy + 1.0f) * 0.5f * (float)(HHH - 1);
        float x0f = floorf(xx), y0f = floorf(yy);
        float wx = xx - x0f, wy = yy - y0f;
        int x0 = (int)x0f, y0 = (int)y0f;

        // x coeffs on the record {h[xb], h[xb+1]} (matches reference gather):
        float axl, axr; int xb;
        if (x0 < 0) {                       // tap0 invalid; tap1 = h[0] iff x0==-1
            axl = (x0 == -1) ? wx : 0.0f; axr = 0.0f; xb = 0;
        } else if (x0 >= WHH - 1) {         // tap1 invalid; tap0 = h[239] iff x0==239
            axl = (x0 == WHH - 1) ? (1.0f - wx) : 0.0f; axr = 0.0f; xb = WHH - 1;
        } else {
            axl = 1.0f - wx; axr = wx; xb = x0;
        }

        float vy0 = (y0 >= 0 && y0 <= HHH - 1) ? 1.0f : 0.0f;
        float vy1 = (y0 + 1 >= 0 && y0 + 1 <= HHH - 1) ? 1.0f : 0.0f;
        int yc0 = min(max(y0, 0), HHH - 1);
        int yc1 = min(max(y0 + 1, 0), HHH - 1);
        float ay0 = (1.0f - wy) * vy0 * bound;
        float ay1 = wy * vy1 * bound;

        cl0[n] = axl * ay0;  cr0[n] = axr * ay0;
        cl1[n] = axl * ay1;  cr1[n] = axr * ay1;
        r0[n] = ((((b * HHH + yc0) * NN + n) * WHH) + xb) * RECU;
        r1[n] = ((((b * HHH + yc1) * NN + n) * WHH) + xb) * RECU;
        bnd[n] = bound;
        sumb += bound;
    }

    float acc[JJ];
    #pragma unroll
    for (int j = 0; j < JJ; ++j) acc[j] = 0.0f;

    #pragma unroll
    for (int n = 0; n < NN; ++n) {
        if (bnd[n] != 0.0f) {
            const uint4* q0 = reinterpret_cast<const uint4*>(ws + r0[n]);
            const uint4* q1 = reinterpret_cast<const uint4*>(ws + r1[n]);
            uint4 a0 = q0[0], a1 = q0[1], a2 = q0[2], a3 = q0[3];
            uint4 b0 = q1[0], b1 = q1[1], b2 = q1[2], b3 = q1[3];
            float c0l = cl0[n], c0r = cr0[n], c1l = cl1[n], c1r = cr1[n];
            unsigned int s0[16] = {a0.x,a0.y,a0.z,a0.w, a1.x,a1.y,a1.z,a1.w,
                                   a2.x,a2.y,a2.z,a2.w, a3.x,a3.y,a3.z,a3.w};
            unsigned int s1[16] = {b0.x,b0.y,b0.z,b0.w, b1.x,b1.y,b1.z,b1.w,
                                   b2.x,b2.y,b2.z,b2.w, b3.x,b3.y,b3.z,b3.w};
            #pragma unroll
            for (int j = 0; j < JJ; ++j) {
                __half2 h0 = *reinterpret_cast<__half2*>(&s0[j]);
                __half2 h1 = *reinterpret_cast<__half2*>(&s1[j]);
                float2 f0 = __half22float2(h0);
                float2 f1 = __half22float2(h1);
                acc[j] += c0l * f0.x + c0r * f0.y + c1l * f1.x + c1r * f1.y;
            }
        }
    }

    float denom = 1.0f / (sumb + 1e-6f);
    size_t outb = (size_t)b * JJ * PP + p;
    #pragma unroll
    for (int j = 0; j < JJ; ++j) {
        float v = acc[j] * denom;
        v = fminf(fmaxf(v, 0.0f), 1.0f);
        out[outb + (size_t)j * PP] = v;
    }
}

extern "C" void kernel_launch(void* const* d_in, const int* in_sizes, int n_in,
                              void* d_out, int out_size, void* d_ws, size_t ws_size,
                              hipStream_t stream) {
    const float* hm    = (const float*)d_in[0];
    const float* Rm    = (const float*)d_in[1];
    const float* Tv    = (const float*)d_in[2];
    const float* fv    = (const float*)d_in[3];
    const float* cv    = (const float*)d_in[4];
    const float* trans = (const float*)d_in[5];
    const float* whv   = (const float*)d_in[6];
    const float* gcv   = (const float*)d_in[7];
    float* out = (float*)d_out;
    unsigned int* ws = (unsigned int*)d_ws;   // 4*128*5*240*64B = 39.3 MB

    // Pass 1: pack heatmaps to f16 x-pair records [B,H,N,W,16u]
    pack_kernel<<<BB * HHH * NN, 256, 0, stream>>>(hm, ws);

    // Pass 2: project + gather + fuse
    int total = BB * PP;
    int block = 256;
    int grid  = (total + block - 1) / block;
    project_kernel<<<grid, block, 0, stream>>>(ws, Rm, Tv, fv, cv, trans, whv, gcv, out);
}